// Round 1
// baseline (533.544 us; speedup 1.0000x reference)
//
#include <hip/hip_runtime.h>

#define NN 100000
#define NE 1600000

__global__ void k_degree(const int* __restrict__ dst, int* __restrict__ deg) {
  int i = blockIdx.x * 256 + threadIdx.x;
  if (i < NE) atomicAdd(&deg[dst[i]], 1);
}

__global__ void k_scan1(const int* __restrict__ deg, int* __restrict__ rowp,
                        int* __restrict__ bsums) {
  __shared__ int sm[256];
  int t = threadIdx.x;
  int i = blockIdx.x * 256 + t;
  int v = (i < NN) ? deg[i] : 0;
  sm[t] = v;
  __syncthreads();
  for (int off = 1; off < 256; off <<= 1) {
    int tmp = (t >= off) ? sm[t - off] : 0;
    __syncthreads();
    sm[t] += tmp;
    __syncthreads();
  }
  if (i < NN) rowp[i] = sm[t] - v;   // exclusive within block
  if (t == 255) bsums[blockIdx.x] = sm[255];
}

__global__ void k_scan2(int* __restrict__ bsums, int nb) {
  __shared__ int sm[512];
  int t = threadIdx.x;
  int v = (t < nb) ? bsums[t] : 0;
  sm[t] = v;
  __syncthreads();
  for (int off = 1; off < 512; off <<= 1) {
    int tmp = (t >= off) ? sm[t - off] : 0;
    __syncthreads();
    sm[t] += tmp;
    __syncthreads();
  }
  if (t < nb) bsums[t] = sm[t] - v;  // exclusive block offsets
}

__global__ void k_scan3(int* __restrict__ rowp, const int* __restrict__ bsums,
                        const int* __restrict__ deg, float* __restrict__ invd) {
  int i = blockIdx.x * 256 + threadIdx.x;
  if (i < NN) {
    rowp[i] += bsums[i >> 8];
    int d = deg[i];
    invd[i] = 1.0f / (float)(d > 0 ? d : 1);
  }
  if (i == 0) rowp[NN] = NE;
}

__global__ void k_fill(const int* __restrict__ src, const int* __restrict__ dst,
                       const int* __restrict__ rowp, int* __restrict__ fillc,
                       int* __restrict__ esrc) {
  int e = blockIdx.x * 256 + threadIdx.x;
  if (e < NE) {
    int d = dst[e];
    int pos = rowp[d] + atomicAdd(&fillc[d], 1);
    esrc[pos] = src[e];
  }
}

// one wave per node, lane = feature (D=64). Register accumulate, no float atomics.
__global__ void k_agg(const float* __restrict__ feat, const int* __restrict__ rowp,
                      const int* __restrict__ esrc, const float* __restrict__ invd,
                      float* __restrict__ agg) {
  int w = (blockIdx.x * blockDim.x + threadIdx.x) >> 6;
  int lane = threadIdx.x & 63;
  if (w >= NN) return;
  int beg = rowp[w], end = rowp[w + 1];
  float acc = 0.f;
  int e = beg;
  for (; e + 1 < end; e += 2) {
    int s0 = esrc[e], s1 = esrc[e + 1];
    float v0 = feat[(size_t)s0 * 64 + lane];
    float v1 = feat[(size_t)s1 * 64 + lane];
    acc += v0 + v1;
  }
  if (e < end) acc += feat[(size_t)esrc[e] * 64 + lane];
  agg[(size_t)w * 64 + lane] = acc * invd[w];
}

// out[n][f] = sum_k [agg|feat][n][k] * [Wl;Wr][k][f] + b[f]  (K=128)
// Tile: 64 nodes x NF feats per block; A in LDS with XOR bank-swizzle; 4x4 per thread.
template <int NF>
__global__ void k_gemm(const float* __restrict__ agg, const float* __restrict__ feat,
                       const float* __restrict__ Wl, const float* __restrict__ Wr,
                       const float* __restrict__ bias, float* __restrict__ out,
                       int relu) {
  constexpr int TXN = NF / 4;       // threads along f
  constexpr int NT = 16 * TXN;      // block threads
  __shared__ float A[64 * 128];     // [node][k], k-XOR-swizzled per row
  __shared__ float W[128 * NF];     // [k][f]
  int tid = threadIdx.x;
  int n0 = blockIdx.x * 64;

  for (int idx = tid; idx < 128 * NF; idx += NT) {
    int k = idx / NF, f = idx % NF;
    W[idx] = (k < 64) ? Wl[k * NF + f] : Wr[(k - 64) * NF + f];
  }
  for (int idx = tid; idx < 64 * 128; idx += NT) {
    int r = idx >> 7, c = idx & 127;
    int n = n0 + r;
    float v = 0.f;
    if (n < NN) v = (c < 64) ? agg[(size_t)n * 64 + c] : feat[(size_t)n * 64 + (c - 64)];
    A[r * 128 + (c ^ (r & 31))] = v;
  }
  __syncthreads();

  int tx = tid % TXN, ty = tid / TXN;  // ty in [0,16)
  float acc[4][4] = {};
  for (int k = 0; k < 128; ++k) {
    float a[4], w[4];
#pragma unroll
    for (int j = 0; j < 4; ++j) {
      int m = ty + 16 * j;
      a[j] = A[m * 128 + (k ^ (m & 31))];
    }
#pragma unroll
    for (int i = 0; i < 4; ++i) w[i] = W[k * NF + tx + TXN * i];
#pragma unroll
    for (int j = 0; j < 4; ++j)
#pragma unroll
      for (int i = 0; i < 4; ++i) acc[j][i] += a[j] * w[i];
  }

#pragma unroll
  for (int j = 0; j < 4; ++j) {
    int n = n0 + ty + 16 * j;
    if (n >= NN) continue;
#pragma unroll
    for (int i = 0; i < 4; ++i) {
      int f = tx + TXN * i;
      float v = acc[j][i] + bias[f];
      if (relu) v = fmaxf(v, 0.f);
      out[(size_t)n * NF + f] = v;
    }
  }
}

extern "C" void kernel_launch(void* const* d_in, const int* in_sizes, int n_in,
                              void* d_out, int out_size, void* d_ws, size_t ws_size,
                              hipStream_t stream) {
  const float* x   = (const float*)d_in[0];
  const int*   ei  = (const int*)d_in[1];
  const float* W1l = (const float*)d_in[2];
  const float* W1r = (const float*)d_in[3];
  const float* b1  = (const float*)d_in[4];
  const float* W2l = (const float*)d_in[5];
  const float* W2r = (const float*)d_in[6];
  const float* b2  = (const float*)d_in[7];
  const int* src = ei;
  const int* dst = ei + NE;
  float* out = (float*)d_out;

  char* ws = (char*)d_ws;
  size_t off = 0;
  auto take = [&](size_t bytes) -> char* {
    char* p = ws + off;
    off = (off + bytes + 255) & ~(size_t)255;
    return p;
  };
  int*   deg   = (int*)take((size_t)NN * 4);
  int*   rowp  = (int*)take((size_t)(NN + 1) * 4);
  int*   fillc = (int*)take((size_t)NN * 4);
  int*   bsums = (int*)take(512 * 4);
  float* invd  = (float*)take((size_t)NN * 4);
  int*   esrc  = (int*)take((size_t)NE * 4);
  float* agg   = (float*)take((size_t)NN * 64 * 4);
  float* h     = (float*)take((size_t)NN * 64 * 4);

  hipMemsetAsync(deg, 0, (size_t)NN * 4, stream);
  hipMemsetAsync(fillc, 0, (size_t)NN * 4, stream);

  int nbE = (NE + 255) / 256;
  int nbN = (NN + 255) / 256;  // 391

  k_degree<<<nbE, 256, 0, stream>>>(dst, deg);
  k_scan1<<<nbN, 256, 0, stream>>>(deg, rowp, bsums);
  k_scan2<<<1, 512, 0, stream>>>(bsums, nbN);
  k_scan3<<<nbN, 256, 0, stream>>>(rowp, bsums, deg, invd);
  k_fill<<<nbE, 256, 0, stream>>>(src, dst, rowp, fillc, esrc);

  // layer 1
  k_agg<<<(NN + 3) / 4, 256, 0, stream>>>(x, rowp, esrc, invd, agg);
  k_gemm<64><<<(NN + 63) / 64, 256, 0, stream>>>(agg, x, W1l, W1r, b1, h, 1);
  // layer 2
  k_agg<<<(NN + 3) / 4, 256, 0, stream>>>(h, rowp, esrc, invd, agg);
  k_gemm<32><<<(NN + 63) / 64, 128, 0, stream>>>(agg, h, W2l, W2r, b2, out, 0);
}

// Round 2
// 485.394 us; speedup vs baseline: 1.0992x; 1.0992x over previous
//
#include <hip/hip_runtime.h>

#define NN 100000
#define NE 1600000

__device__ __forceinline__ float b2f(unsigned short u) {
  return __uint_as_float(((unsigned)u) << 16);
}
__device__ __forceinline__ unsigned short f2b(float f) {
  unsigned b = __float_as_uint(f);
  unsigned r = b + 0x7FFF + ((b >> 16) & 1);  // RNE
  return (unsigned short)(r >> 16);
}

__global__ void k_cvt(const float* __restrict__ in, unsigned short* __restrict__ out) {
  int i = (blockIdx.x * 256 + threadIdx.x) * 4;
  float4 v = *(const float4*)(in + i);
  ushort4 o;
  o.x = f2b(v.x); o.y = f2b(v.y); o.z = f2b(v.z); o.w = f2b(v.w);
  *(ushort4*)(out + i) = o;
}

__global__ void k_degree(const int* __restrict__ dst, int* __restrict__ deg) {
  int i = blockIdx.x * 256 + threadIdx.x;
  if (i < NE) atomicAdd(&deg[dst[i]], 1);
}

__global__ void k_scan1(const int* __restrict__ deg, int* __restrict__ rowp,
                        int* __restrict__ bsums) {
  __shared__ int sm[256];
  int t = threadIdx.x;
  int i = blockIdx.x * 256 + t;
  int v = (i < NN) ? deg[i] : 0;
  sm[t] = v;
  __syncthreads();
  for (int off = 1; off < 256; off <<= 1) {
    int tmp = (t >= off) ? sm[t - off] : 0;
    __syncthreads();
    sm[t] += tmp;
    __syncthreads();
  }
  if (i < NN) rowp[i] = sm[t] - v;
  if (t == 255) bsums[blockIdx.x] = sm[255];
}

__global__ void k_scan2(int* __restrict__ bsums, int nb) {
  __shared__ int sm[512];
  int t = threadIdx.x;
  int v = (t < nb) ? bsums[t] : 0;
  sm[t] = v;
  __syncthreads();
  for (int off = 1; off < 512; off <<= 1) {
    int tmp = (t >= off) ? sm[t - off] : 0;
    __syncthreads();
    sm[t] += tmp;
    __syncthreads();
  }
  if (t < nb) bsums[t] = sm[t] - v;
}

__global__ void k_scan3(int* __restrict__ rowp, const int* __restrict__ bsums,
                        const int* __restrict__ deg, float* __restrict__ invd) {
  int i = blockIdx.x * 256 + threadIdx.x;
  if (i < NN) {
    rowp[i] += bsums[i >> 8];
    int d = deg[i];
    invd[i] = 1.0f / (float)(d > 0 ? d : 1);
  }
  if (i == 0) rowp[NN] = NE;
}

__global__ void k_fill(const int* __restrict__ src, const int* __restrict__ dst,
                       int* __restrict__ cursor, int* __restrict__ esrc) {
  int e = blockIdx.x * 256 + threadIdx.x;
  if (e < NE) {
    int pos = atomicAdd(&cursor[dst[e]], 1);
    esrc[pos] = src[e];
  }
}

// one wave per node, lane = feature. Scalar-batched indices, 8 gathers in flight.
__global__ void k_agg(const unsigned short* __restrict__ fb, const int* __restrict__ rowp,
                      const int* __restrict__ esrc, const float* __restrict__ invd,
                      float* __restrict__ agg) {
  int w = (blockIdx.x * blockDim.x + threadIdx.x) >> 6;
  int lane = threadIdx.x & 63;
  int beg = __builtin_amdgcn_readfirstlane(rowp[w]);
  int end = __builtin_amdgcn_readfirstlane(rowp[w + 1]);
  float acc = 0.f;
  int e = beg;
  for (; e + 8 <= end; e += 8) {
    float v[8];
#pragma unroll
    for (int j = 0; j < 8; ++j) {
      int s = esrc[e + j];  // uniform -> scalar loads, batched
      v[j] = b2f(fb[(size_t)s * 64 + lane]);
    }
    acc += ((v[0] + v[1]) + (v[2] + v[3])) + ((v[4] + v[5]) + (v[6] + v[7]));
  }
  for (; e + 4 <= end; e += 4) {
    float v[4];
#pragma unroll
    for (int j = 0; j < 4; ++j) {
      int s = esrc[e + j];
      v[j] = b2f(fb[(size_t)s * 64 + lane]);
    }
    acc += (v[0] + v[1]) + (v[2] + v[3]);
  }
  for (; e < end; ++e) acc += b2f(fb[(size_t)esrc[e] * 64 + lane]);
  agg[(size_t)w * 64 + lane] = acc * invd[w];
}

// out[n][f] = sum_k [agg|feat][n][k] * [Wl;Wr][k][f] + b[f]  (K=128)
template <int NF>
__global__ void k_gemm(const float* __restrict__ agg, const float* __restrict__ feat,
                       const float* __restrict__ Wl, const float* __restrict__ Wr,
                       const float* __restrict__ bias, float* __restrict__ out,
                       unsigned short* __restrict__ ob, int relu) {
  constexpr int TXN = NF / 4;
  constexpr int NT = 16 * TXN;
  __shared__ float A[64 * 128];
  __shared__ float W[128 * NF];
  int tid = threadIdx.x;
  int n0 = blockIdx.x * 64;

  for (int idx = tid; idx < 128 * NF; idx += NT) {
    int k = idx / NF, f = idx % NF;
    W[idx] = (k < 64) ? Wl[k * NF + f] : Wr[(k - 64) * NF + f];
  }
  for (int idx = tid; idx < 64 * 128; idx += NT) {
    int r = idx >> 7, c = idx & 127;
    int n = n0 + r;
    float v = 0.f;
    if (n < NN) v = (c < 64) ? agg[(size_t)n * 64 + c] : feat[(size_t)n * 64 + (c - 64)];
    A[r * 128 + (c ^ (r & 31))] = v;
  }
  __syncthreads();

  int tx = tid % TXN, ty = tid / TXN;
  float acc[4][4] = {};
  for (int k = 0; k < 128; ++k) {
    float a[4], w[4];
#pragma unroll
    for (int j = 0; j < 4; ++j) {
      int m = ty + 16 * j;
      a[j] = A[m * 128 + (k ^ (m & 31))];
    }
#pragma unroll
    for (int i = 0; i < 4; ++i) w[i] = W[k * NF + tx + TXN * i];
#pragma unroll
    for (int j = 0; j < 4; ++j)
#pragma unroll
      for (int i = 0; i < 4; ++i) acc[j][i] += a[j] * w[i];
  }

#pragma unroll
  for (int j = 0; j < 4; ++j) {
    int n = n0 + ty + 16 * j;
    if (n >= NN) continue;
#pragma unroll
    for (int i = 0; i < 4; ++i) {
      int f = tx + TXN * i;
      float v = acc[j][i] + bias[f];
      if (relu) v = fmaxf(v, 0.f);
      out[(size_t)n * NF + f] = v;
      if (ob) ob[(size_t)n * NF + f] = f2b(v);
    }
  }
}

extern "C" void kernel_launch(void* const* d_in, const int* in_sizes, int n_in,
                              void* d_out, int out_size, void* d_ws, size_t ws_size,
                              hipStream_t stream) {
  const float* x   = (const float*)d_in[0];
  const int*   ei  = (const int*)d_in[1];
  const float* W1l = (const float*)d_in[2];
  const float* W1r = (const float*)d_in[3];
  const float* b1  = (const float*)d_in[4];
  const float* W2l = (const float*)d_in[5];
  const float* W2r = (const float*)d_in[6];
  const float* b2  = (const float*)d_in[7];
  const int* src = ei;
  const int* dst = ei + NE;
  float* out = (float*)d_out;

  char* ws = (char*)d_ws;
  size_t off = 0;
  auto take = [&](size_t bytes) -> char* {
    char* p = ws + off;
    off = (off + bytes + 255) & ~(size_t)255;
    return p;
  };
  int*   deg    = (int*)take((size_t)NN * 4);
  int*   rowp   = (int*)take((size_t)(NN + 1) * 4);
  int*   cursor = (int*)take((size_t)NN * 4);
  int*   bsums  = (int*)take(512 * 4);
  float* invd   = (float*)take((size_t)NN * 4);
  int*   esrc   = (int*)take((size_t)NE * 4);
  float* agg    = (float*)take((size_t)NN * 64 * 4);
  float* h      = (float*)take((size_t)NN * 64 * 4);
  unsigned short* xb = (unsigned short*)take((size_t)NN * 64 * 2);
  unsigned short* hb = (unsigned short*)take((size_t)NN * 64 * 2);

  hipMemsetAsync(deg, 0, (size_t)NN * 4, stream);

  int nbE = (NE + 255) / 256;
  int nbN = (NN + 255) / 256;  // 391

  k_cvt<<<(NN * 64) / 1024, 256, 0, stream>>>(x, xb);
  k_degree<<<nbE, 256, 0, stream>>>(dst, deg);
  k_scan1<<<nbN, 256, 0, stream>>>(deg, rowp, bsums);
  k_scan2<<<1, 512, 0, stream>>>(bsums, nbN);
  k_scan3<<<nbN, 256, 0, stream>>>(rowp, bsums, deg, invd);
  hipMemcpyAsync(cursor, rowp, (size_t)NN * 4, hipMemcpyDeviceToDevice, stream);
  k_fill<<<nbE, 256, 0, stream>>>(src, dst, cursor, esrc);

  // layer 1
  k_agg<<<(NN * 64) / 256, 256, 0, stream>>>(xb, rowp, esrc, invd, agg);
  k_gemm<64><<<(NN + 63) / 64, 256, 0, stream>>>(agg, x, W1l, W1r, b1, h, hb, 1);
  // layer 2
  k_agg<<<(NN * 64) / 256, 256, 0, stream>>>(hb, rowp, esrc, invd, agg);
  k_gemm<32><<<(NN + 63) / 64, 128, 0, stream>>>(agg, h, W2l, W2r, b2, out, nullptr, 0);
}

// Round 3
// 351.646 us; speedup vs baseline: 1.5173x; 1.3803x over previous
//
#include <hip/hip_runtime.h>

#define NN 100000
#define NE 1600000
#define NBK 196        // ceil(100000/512) buckets of 512 nodes
#define CAPB 12288     // per-bucket edge capacity (mean 8192, +45 sigma)

__device__ __forceinline__ unsigned short f2b(float f) {
  unsigned b = __float_as_uint(f);
  unsigned r = b + 0x7FFF + ((b >> 16) & 1);  // RNE
  return (unsigned short)(r >> 16);
}

__global__ void k_cvt(const float* __restrict__ in, unsigned short* __restrict__ out) {
  int i = (blockIdx.x * 256 + threadIdx.x) * 4;
  float4 v = *(const float4*)(in + i);
  ushort4 o;
  o.x = f2b(v.x); o.y = f2b(v.y); o.z = f2b(v.z); o.w = f2b(v.w);
  *(ushort4*)(out + i) = o;
}

// Pass A: partition edges into NBK buckets by dst>>9; payload (src<<9)|(dst&511).
__global__ void k_partA(const int* __restrict__ src, const int* __restrict__ dst,
                        int* __restrict__ gcur, unsigned* __restrict__ pairbuf) {
  __shared__ int hist[NBK], base[NBK], lofs[NBK];
  int t = threadIdx.x;
  for (int i = t; i < NBK; i += 256) hist[i] = 0;
  __syncthreads();
  unsigned pk[16]; int bk[16];
  int e0 = blockIdx.x * 4096 + t;
#pragma unroll
  for (int j = 0; j < 16; ++j) {
    int e = e0 + j * 256;
    if (e < NE) {
      int d = dst[e], s = src[e];
      bk[j] = d >> 9;
      pk[j] = ((unsigned)s << 9) | (unsigned)(d & 511);
      atomicAdd(&hist[bk[j]], 1);
    } else bk[j] = -1;
  }
  __syncthreads();
  for (int i = t; i < NBK; i += 256) {
    base[i] = atomicAdd(&gcur[i], hist[i]);
    lofs[i] = 0;
  }
  __syncthreads();
#pragma unroll
  for (int j = 0; j < 16; ++j) {
    if (bk[j] >= 0) {
      int lp = base[bk[j]] + atomicAdd(&lofs[bk[j]], 1);
      if (lp < CAPB) pairbuf[(size_t)bk[j] * CAPB + lp] = pk[j];
    }
  }
}

// Pass B: one block per bucket. Count -> prefix -> LDS scatter -> coalesced writeout.
__global__ void k_partB(const unsigned* __restrict__ pairbuf, const int* __restrict__ gcur,
                        int* __restrict__ esrc, int* __restrict__ rowbeg,
                        int* __restrict__ rowend, float* __restrict__ invd) {
  __shared__ int cnt[512], pre[512], cur[512], ssum[256];
  __shared__ int ebuf[CAPB];
  int b = blockIdx.x, t = threadIdx.x;
  int cb = gcur[b]; if (cb > CAPB) cb = CAPB;
  cnt[t] = 0; cnt[t + 256] = 0;
  __syncthreads();
  const unsigned* pb = pairbuf + (size_t)b * CAPB;
  for (int i = t; i < cb; i += 256) atomicAdd(&cnt[pb[i] & 511], 1);
  __syncthreads();
  int a0 = cnt[2 * t], a1 = cnt[2 * t + 1];
  ssum[t] = a0 + a1;
  __syncthreads();
  for (int off = 1; off < 256; off <<= 1) {
    int tmp = (t >= off) ? ssum[t - off] : 0;
    __syncthreads();
    ssum[t] += tmp;
    __syncthreads();
  }
  int ex = ssum[t] - (a0 + a1);
  pre[2 * t] = ex;       cur[2 * t] = ex;
  pre[2 * t + 1] = ex + a0; cur[2 * t + 1] = ex + a0;
  __syncthreads();
  for (int l = t; l < 512; l += 256) {
    int n = b * 512 + l;
    if (n < NN) {
      int d = cnt[l];
      rowbeg[n] = b * CAPB + pre[l];
      rowend[n] = b * CAPB + pre[l] + d;
      invd[n] = 1.0f / (float)(d > 0 ? d : 1);
    }
  }
  for (int i = t; i < cb; i += 256) {
    unsigned p = pb[i];
    int pos = atomicAdd(&cur[p & 511], 1);
    ebuf[pos] = (int)(p >> 9);
  }
  __syncthreads();
  for (int i = t; i < cb; i += 256) esrc[(size_t)b * CAPB + i] = ebuf[i];
}

// One wave per node; half-wave per edge (2 edges per load instr), dword bf16-pair loads.
__global__ void k_agg(const unsigned* __restrict__ fb32, const int* __restrict__ rowbeg,
                      const int* __restrict__ rowend, const int* __restrict__ esrc,
                      const float* __restrict__ invd, float* __restrict__ agg) {
  int w = (blockIdx.x * blockDim.x + threadIdx.x) >> 6;
  int lane = threadIdx.x & 63;
  int c = lane & 31, h = lane >> 5;
  int beg = __builtin_amdgcn_readfirstlane(rowbeg[w]);
  int end = __builtin_amdgcn_readfirstlane(rowend[w]);
  int nume = end - beg;
  float a0 = 0.f, a1 = 0.f;
  int e = beg;
  int pairend = beg + (nume & ~1);
  for (; e + 16 <= pairend; e += 16) {
    unsigned v[8];
#pragma unroll
    for (int j = 0; j < 8; ++j) {
      int s = esrc[e + 2 * j + h];
      v[j] = fb32[(size_t)s * 32 + c];
    }
#pragma unroll
    for (int j = 0; j < 8; ++j) {
      a0 += __uint_as_float(v[j] << 16);
      a1 += __uint_as_float(v[j] & 0xFFFF0000u);
    }
  }
  for (; e < pairend; e += 2) {
    int s = esrc[e + h];
    unsigned v = fb32[(size_t)s * 32 + c];
    a0 += __uint_as_float(v << 16);
    a1 += __uint_as_float(v & 0xFFFF0000u);
  }
  if ((nume & 1) && h == 0) {
    int s = esrc[end - 1];
    unsigned v = fb32[(size_t)s * 32 + c];
    a0 += __uint_as_float(v << 16);
    a1 += __uint_as_float(v & 0xFFFF0000u);
  }
  a0 += __shfl_xor(a0, 32);
  a1 += __shfl_xor(a1, 32);
  if (h == 0) {
    float inv = invd[w];
    ((float2*)agg)[(size_t)w * 32 + c] = make_float2(a0 * inv, a1 * inv);
  }
}

// out[n][f] = sum_k [agg|feat][n][k] * [Wl;Wr][k][f] + b[f]  (K=128)
template <int NF>
__global__ void k_gemm(const float* __restrict__ agg, const float* __restrict__ feat,
                       const float* __restrict__ Wl, const float* __restrict__ Wr,
                       const float* __restrict__ bias, float* __restrict__ out,
                       unsigned short* __restrict__ ob, int relu) {
  constexpr int TXN = NF / 4;
  constexpr int NT = 16 * TXN;
  __shared__ float A[64 * 128];
  __shared__ float W[128 * NF];
  int tid = threadIdx.x;
  int n0 = blockIdx.x * 64;

  for (int idx = tid; idx < 128 * NF; idx += NT) {
    int k = idx / NF, f = idx % NF;
    W[idx] = (k < 64) ? Wl[k * NF + f] : Wr[(k - 64) * NF + f];
  }
  for (int idx = tid; idx < 64 * 128; idx += NT) {
    int r = idx >> 7, c = idx & 127;
    int n = n0 + r;
    float v = 0.f;
    if (n < NN) v = (c < 64) ? agg[(size_t)n * 64 + c] : feat[(size_t)n * 64 + (c - 64)];
    A[r * 128 + (c ^ (r & 31))] = v;
  }
  __syncthreads();

  int tx = tid % TXN, ty = tid / TXN;
  float acc[4][4] = {};
  for (int k = 0; k < 128; ++k) {
    float a[4], w[4];
#pragma unroll
    for (int j = 0; j < 4; ++j) {
      int m = ty + 16 * j;
      a[j] = A[m * 128 + (k ^ (m & 31))];
    }
#pragma unroll
    for (int i = 0; i < 4; ++i) w[i] = W[k * NF + tx + TXN * i];
#pragma unroll
    for (int j = 0; j < 4; ++j)
#pragma unroll
      for (int i = 0; i < 4; ++i) acc[j][i] += a[j] * w[i];
  }

#pragma unroll
  for (int j = 0; j < 4; ++j) {
    int n = n0 + ty + 16 * j;
    if (n >= NN) continue;
#pragma unroll
    for (int i = 0; i < 4; ++i) {
      int f = tx + TXN * i;
      float v = acc[j][i] + bias[f];
      if (relu) v = fmaxf(v, 0.f);
      out[(size_t)n * NF + f] = v;
      if (ob) ob[(size_t)n * NF + f] = f2b(v);
    }
  }
}

extern "C" void kernel_launch(void* const* d_in, const int* in_sizes, int n_in,
                              void* d_out, int out_size, void* d_ws, size_t ws_size,
                              hipStream_t stream) {
  const float* x   = (const float*)d_in[0];
  const int*   ei  = (const int*)d_in[1];
  const float* W1l = (const float*)d_in[2];
  const float* W1r = (const float*)d_in[3];
  const float* b1  = (const float*)d_in[4];
  const float* W2l = (const float*)d_in[5];
  const float* W2r = (const float*)d_in[6];
  const float* b2  = (const float*)d_in[7];
  const int* src = ei;
  const int* dst = ei + NE;
  float* out = (float*)d_out;

  char* ws = (char*)d_ws;
  size_t off = 0;
  auto take = [&](size_t bytes) -> char* {
    char* p = ws + off;
    off = (off + bytes + 255) & ~(size_t)255;
    return p;
  };
  int*      gcur    = (int*)take((size_t)NBK * 4);
  unsigned* pairbuf = (unsigned*)take((size_t)NBK * CAPB * 4);
  int*      esrc    = (int*)take((size_t)NBK * CAPB * 4);
  int*      rowbeg  = (int*)take((size_t)NN * 4);
  int*      rowend  = (int*)take((size_t)NN * 4);
  float*    invd    = (float*)take((size_t)NN * 4);
  float*    agg     = (float*)take((size_t)NN * 64 * 4);
  float*    h       = (float*)take((size_t)NN * 64 * 4);
  unsigned short* xb = (unsigned short*)take((size_t)NN * 64 * 2);
  unsigned short* hb = (unsigned short*)take((size_t)NN * 64 * 2);

  hipMemsetAsync(gcur, 0, (size_t)NBK * 4, stream);

  k_cvt<<<(NN * 64) / 1024, 256, 0, stream>>>(x, xb);
  k_partA<<<(NE + 4095) / 4096, 256, 0, stream>>>(src, dst, gcur, pairbuf);
  k_partB<<<NBK, 256, 0, stream>>>(pairbuf, gcur, esrc, rowbeg, rowend, invd);

  // layer 1
  k_agg<<<(NN * 64) / 256, 256, 0, stream>>>((const unsigned*)xb, rowbeg, rowend, esrc, invd, agg);
  k_gemm<64><<<(NN + 63) / 64, 256, 0, stream>>>(agg, x, W1l, W1r, b1, h, hb, 1);
  // layer 2
  k_agg<<<(NN * 64) / 256, 256, 0, stream>>>((const unsigned*)hb, rowbeg, rowend, esrc, invd, agg);
  k_gemm<32><<<(NN + 63) / 64, 128, 0, stream>>>(agg, h, W2l, W2r, b2, out, nullptr, 0);
}

// Round 4
// 199.244 us; speedup vs baseline: 2.6778x; 1.7649x over previous
//
#include <hip/hip_runtime.h>

#define NN 100000
#define NE 1600000
#define NBK 196        // ceil(100000/512) buckets of 512 nodes
#define CAPB 12288     // per-bucket edge capacity (mean 8192)

typedef __attribute__((ext_vector_type(8))) short bf16x8;
typedef __attribute__((ext_vector_type(4))) float f32x4;
typedef unsigned short ushort_t;

__device__ __forceinline__ unsigned short f2b(float f) {
  unsigned b = __float_as_uint(f);
  unsigned r = b + 0x7FFF + ((b >> 16) & 1);  // RNE
  return (unsigned short)(r >> 16);
}

__global__ void k_cvt(const float* __restrict__ in, unsigned short* __restrict__ out) {
  int i = (blockIdx.x * 256 + threadIdx.x) * 4;
  float4 v = *(const float4*)(in + i);
  ushort4 o;
  o.x = f2b(v.x); o.y = f2b(v.y); o.z = f2b(v.z); o.w = f2b(v.w);
  *(ushort4*)(out + i) = o;
}

// WT[f][k] bf16 from Wl/Wr f32 ([k][f], k<64 -> Wl)
__global__ void k_buildWT(const float* __restrict__ Wl, const float* __restrict__ Wr,
                          unsigned short* __restrict__ WT, int NF) {
  int t = blockIdx.x * 256 + threadIdx.x;
  if (t >= NF * 128) return;
  int f = t >> 7, k = t & 127;
  float v = (k < 64) ? Wl[k * NF + f] : Wr[(k - 64) * NF + f];
  WT[t] = f2b(v);
}

// Pass A: partition edges into NBK buckets by dst>>9; payload (src<<9)|(dst&511).
__global__ void k_partA(const int* __restrict__ src, const int* __restrict__ dst,
                        int* __restrict__ gcur, unsigned* __restrict__ pairbuf) {
  __shared__ int hist[NBK], base[NBK], lofs[NBK];
  int t = threadIdx.x;
  for (int i = t; i < NBK; i += 256) hist[i] = 0;
  __syncthreads();
  unsigned pk[16]; int bk[16];
  int e0 = blockIdx.x * 4096 + t;
#pragma unroll
  for (int j = 0; j < 16; ++j) {
    int e = e0 + j * 256;
    if (e < NE) {
      int d = dst[e], s = src[e];
      bk[j] = d >> 9;
      pk[j] = ((unsigned)s << 9) | (unsigned)(d & 511);
      atomicAdd(&hist[bk[j]], 1);
    } else bk[j] = -1;
  }
  __syncthreads();
  for (int i = t; i < NBK; i += 256) {
    base[i] = atomicAdd(&gcur[i], hist[i]);
    lofs[i] = 0;
  }
  __syncthreads();
#pragma unroll
  for (int j = 0; j < 16; ++j) {
    if (bk[j] >= 0) {
      int lp = base[bk[j]] + atomicAdd(&lofs[bk[j]], 1);
      if (lp < CAPB) pairbuf[(size_t)bk[j] * CAPB + lp] = pk[j];
    }
  }
}

// Pass B: one block per bucket. Count -> prefix -> LDS scatter -> coalesced writeout.
__global__ void k_partB(const unsigned* __restrict__ pairbuf, const int* __restrict__ gcur,
                        int* __restrict__ esrc, int* __restrict__ rowbeg,
                        int* __restrict__ rowend, float* __restrict__ invd) {
  __shared__ int cnt[512], pre[512], cur[512], ssum[256];
  __shared__ int ebuf[CAPB];
  int b = blockIdx.x, t = threadIdx.x;
  int cb = gcur[b]; if (cb > CAPB) cb = CAPB;
  cnt[t] = 0; cnt[t + 256] = 0;
  __syncthreads();
  const unsigned* pb = pairbuf + (size_t)b * CAPB;
  for (int i = t; i < cb; i += 256) atomicAdd(&cnt[pb[i] & 511], 1);
  __syncthreads();
  int a0 = cnt[2 * t], a1 = cnt[2 * t + 1];
  ssum[t] = a0 + a1;
  __syncthreads();
  for (int off = 1; off < 256; off <<= 1) {
    int tmp = (t >= off) ? ssum[t - off] : 0;
    __syncthreads();
    ssum[t] += tmp;
    __syncthreads();
  }
  int ex = ssum[t] - (a0 + a1);
  pre[2 * t] = ex;       cur[2 * t] = ex;
  pre[2 * t + 1] = ex + a0; cur[2 * t + 1] = ex + a0;
  __syncthreads();
  for (int l = t; l < 512; l += 256) {
    int n = b * 512 + l;
    if (n < NN) {
      int d = cnt[l];
      rowbeg[n] = b * CAPB + pre[l];
      rowend[n] = b * CAPB + pre[l] + d;
      invd[n] = 1.0f / (float)(d > 0 ? d : 1);
    }
  }
  for (int i = t; i < cb; i += 256) {
    unsigned p = pb[i];
    int pos = atomicAdd(&cur[p & 511], 1);
    ebuf[pos] = (int)(p >> 9);
  }
  __syncthreads();
  for (int i = t; i < cb; i += 256) esrc[(size_t)b * CAPB + i] = ebuf[i];
}

// One wave per node; half-wave per edge, dword bf16-pair loads; bf16 output.
__global__ void k_agg(const unsigned* __restrict__ fb32, const int* __restrict__ rowbeg,
                      const int* __restrict__ rowend, const int* __restrict__ esrc,
                      const float* __restrict__ invd, unsigned* __restrict__ aggb32) {
  int w = (blockIdx.x * blockDim.x + threadIdx.x) >> 6;
  int lane = threadIdx.x & 63;
  int c = lane & 31, h = lane >> 5;
  int beg = __builtin_amdgcn_readfirstlane(rowbeg[w]);
  int end = __builtin_amdgcn_readfirstlane(rowend[w]);
  int nume = end - beg;
  float a0 = 0.f, a1 = 0.f;
  int e = beg;
  int pairend = beg + (nume & ~1);
  for (; e + 16 <= pairend; e += 16) {
    unsigned v[8];
#pragma unroll
    for (int j = 0; j < 8; ++j) {
      int s = esrc[e + 2 * j + h];
      v[j] = fb32[(size_t)s * 32 + c];
    }
#pragma unroll
    for (int j = 0; j < 8; ++j) {
      a0 += __uint_as_float(v[j] << 16);
      a1 += __uint_as_float(v[j] & 0xFFFF0000u);
    }
  }
  for (; e < pairend; e += 2) {
    int s = esrc[e + h];
    unsigned v = fb32[(size_t)s * 32 + c];
    a0 += __uint_as_float(v << 16);
    a1 += __uint_as_float(v & 0xFFFF0000u);
  }
  if ((nume & 1) && h == 0) {
    int s = esrc[end - 1];
    unsigned v = fb32[(size_t)s * 32 + c];
    a0 += __uint_as_float(v << 16);
    a1 += __uint_as_float(v & 0xFFFF0000u);
  }
  a0 += __shfl_xor(a0, 32);
  a1 += __shfl_xor(a1, 32);
  if (h == 0) {
    float inv = invd[w];
    unsigned lo = f2b(a0 * inv), hi = f2b(a1 * inv);
    aggb32[(size_t)w * 32 + c] = lo | (hi << 16);
  }
}

// MFMA GEMM: out[n][f] = sum_k [aggb|featb][n][k] * WT[f][k] + bias[f], K=128 bf16.
// Tile 64 nodes x NF; 4 waves; A and W in LDS with 16B-slot XOR swizzle.
template <int NF>
__global__ __launch_bounds__(256) void k_gemm(
    const unsigned short* __restrict__ aggb, const unsigned short* __restrict__ featb,
    const unsigned short* __restrict__ WT, const float* __restrict__ bias,
    float* __restrict__ out, unsigned short* __restrict__ ob, int relu) {
  __shared__ unsigned short As[64 * 128];
  __shared__ unsigned short Ws[NF * 128];
  int tid = threadIdx.x;
  int n0 = blockIdx.x * 64;
  int lane = tid & 63, wr = tid >> 6;

  // stage A: 64 rows x 16 slots of 8 bf16; slot<8 from aggb, else featb
  for (int cch = tid; cch < 64 * 16; cch += 256) {
    int r = cch >> 4, s = cch & 15;
    int n = n0 + r;
    bf16x8 v = {0, 0, 0, 0, 0, 0, 0, 0};
    if (n < NN) {
      const unsigned short* p = (s < 8) ? (aggb + (size_t)n * 64 + s * 8)
                                        : (featb + (size_t)n * 64 + (s - 8) * 8);
      v = *(const bf16x8*)p;
    }
    *(bf16x8*)(&As[r * 128 + ((s ^ (r & 15)) << 3)]) = v;
  }
  // stage W: NF rows x 16 slots
  for (int cch = tid; cch < NF * 16; cch += 256) {
    int f = cch >> 4, s = cch & 15;
    bf16x8 v = *(const bf16x8*)(WT + f * 128 + s * 8);
    *(bf16x8*)(&Ws[f * 128 + ((s ^ (f & 15)) << 3)]) = v;
  }
  __syncthreads();

  int l15 = lane & 15, lg = lane >> 4;
  int arow = wr * 16 + l15;
  f32x4 acc[NF / 16];
#pragma unroll
  for (int ct = 0; ct < NF / 16; ++ct) acc[ct] = (f32x4){0.f, 0.f, 0.f, 0.f};

#pragma unroll
  for (int k0 = 0; k0 < 4; ++k0) {
    int sa = k0 * 4 + lg;
    bf16x8 a = *(const bf16x8*)(&As[arow * 128 + ((sa ^ (arow & 15)) << 3)]);
#pragma unroll
    for (int ct = 0; ct < NF / 16; ++ct) {
      int bcol = ct * 16 + l15;
      bf16x8 b = *(const bf16x8*)(&Ws[bcol * 128 + ((sa ^ (bcol & 15)) << 3)]);
      acc[ct] = __builtin_amdgcn_mfma_f32_16x16x32_bf16(a, b, acc[ct], 0, 0, 0);
    }
  }

#pragma unroll
  for (int ct = 0; ct < NF / 16; ++ct) {
    int f = ct * 16 + l15;
    float bv = bias[f];
#pragma unroll
    for (int r = 0; r < 4; ++r) {
      int n = n0 + wr * 16 + lg * 4 + r;
      if (n >= NN) continue;
      float v = acc[ct][r] + bv;
      if (relu) v = fmaxf(v, 0.f);
      if (out) out[(size_t)n * NF + f] = v;
      if (ob) ob[(size_t)n * NF + f] = f2b(v);
    }
  }
}

extern "C" void kernel_launch(void* const* d_in, const int* in_sizes, int n_in,
                              void* d_out, int out_size, void* d_ws, size_t ws_size,
                              hipStream_t stream) {
  const float* x   = (const float*)d_in[0];
  const int*   ei  = (const int*)d_in[1];
  const float* W1l = (const float*)d_in[2];
  const float* W1r = (const float*)d_in[3];
  const float* b1  = (const float*)d_in[4];
  const float* W2l = (const float*)d_in[5];
  const float* W2r = (const float*)d_in[6];
  const float* b2  = (const float*)d_in[7];
  const int* src = ei;
  const int* dst = ei + NE;
  float* out = (float*)d_out;

  char* ws = (char*)d_ws;
  size_t off = 0;
  auto take = [&](size_t bytes) -> char* {
    char* p = ws + off;
    off = (off + bytes + 255) & ~(size_t)255;
    return p;
  };
  int*      gcur    = (int*)take((size_t)NBK * 4);
  unsigned* pairbuf = (unsigned*)take((size_t)NBK * CAPB * 4);
  int*      esrc    = (int*)take((size_t)NBK * CAPB * 4);
  int*      rowbeg  = (int*)take((size_t)NN * 4);
  int*      rowend  = (int*)take((size_t)NN * 4);
  float*    invd    = (float*)take((size_t)NN * 4);
  unsigned short* aggb = (unsigned short*)take((size_t)NN * 64 * 2);
  unsigned short* xb   = (unsigned short*)take((size_t)NN * 64 * 2);
  unsigned short* hb   = (unsigned short*)take((size_t)NN * 64 * 2);
  unsigned short* WT1  = (unsigned short*)take((size_t)64 * 128 * 2);
  unsigned short* WT2  = (unsigned short*)take((size_t)32 * 128 * 2);

  hipMemsetAsync(gcur, 0, (size_t)NBK * 4, stream);

  k_cvt<<<(NN * 64) / 1024, 256, 0, stream>>>(x, xb);
  k_buildWT<<<(64 * 128 + 255) / 256, 256, 0, stream>>>(W1l, W1r, WT1, 64);
  k_buildWT<<<(32 * 128 + 255) / 256, 256, 0, stream>>>(W2l, W2r, WT2, 32);
  k_partA<<<(NE + 4095) / 4096, 256, 0, stream>>>(src, dst, gcur, pairbuf);
  k_partB<<<NBK, 256, 0, stream>>>(pairbuf, gcur, esrc, rowbeg, rowend, invd);

  int nbG = (NN + 63) / 64;  // 1563
  // layer 1
  k_agg<<<(NN * 64) / 256, 256, 0, stream>>>((const unsigned*)xb, rowbeg, rowend, esrc,
                                             invd, (unsigned*)aggb);
  k_gemm<64><<<nbG, 256, 0, stream>>>(aggb, xb, WT1, b1, nullptr, hb, 1);
  // layer 2
  k_agg<<<(NN * 64) / 256, 256, 0, stream>>>((const unsigned*)hb, rowbeg, rowend, esrc,
                                             invd, (unsigned*)aggb);
  k_gemm<32><<<nbG, 256, 0, stream>>>(aggb, hb, WT2, b2, out, nullptr, 0);
}

// Round 6
// 172.694 us; speedup vs baseline: 3.0895x; 1.1537x over previous
//
#include <hip/hip_runtime.h>

#define NN 100000
#define NE 1600000
#define NBK 196        // ceil(100000/512) buckets of 512 nodes
#define CAPB 12288     // per-bucket edge capacity (mean 8192)
#define CVTB 6250      // (NN*64)/1024 blocks for x->bf16

typedef __attribute__((ext_vector_type(8))) short bf16x8;
typedef __attribute__((ext_vector_type(4))) float f32x4;

__device__ __forceinline__ unsigned short f2b(float f) {
  unsigned b = __float_as_uint(f);
  unsigned r = b + 0x7FFF + ((b >> 16) & 1);  // RNE
  return (unsigned short)(r >> 16);
}

// Fused prologue: [0,CVTB) x->bf16 | CVTB: WT1 | CVTB+1: WT2 | rest: partA
__global__ void k_pre(const float* __restrict__ x, unsigned short* __restrict__ xb,
                      const float* __restrict__ W1l, const float* __restrict__ W1r,
                      unsigned short* __restrict__ WT1,
                      const float* __restrict__ W2l, const float* __restrict__ W2r,
                      unsigned short* __restrict__ WT2,
                      const int* __restrict__ src, const int* __restrict__ dst,
                      int* __restrict__ gcur, unsigned* __restrict__ pairbuf) {
  __shared__ int hist[NBK], base[NBK], lofs[NBK];
  int t = threadIdx.x;
  int b = blockIdx.x;
  if (b < CVTB) {
    int i = (b * 256 + t) * 4;
    float4 v = *(const float4*)(x + i);
    ushort4 o;
    o.x = f2b(v.x); o.y = f2b(v.y); o.z = f2b(v.z); o.w = f2b(v.w);
    *(ushort4*)(xb + i) = o;
    return;
  }
  if (b == CVTB) {
    for (int i = t; i < 64 * 128; i += 256) {
      int f = i >> 7, k = i & 127;
      WT1[i] = f2b((k < 64) ? W1l[k * 64 + f] : W1r[(k - 64) * 64 + f]);
    }
    return;
  }
  if (b == CVTB + 1) {
    for (int i = t; i < 32 * 128; i += 256) {
      int f = i >> 7, k = i & 127;
      WT2[i] = f2b((k < 64) ? W2l[k * 32 + f] : W2r[(k - 64) * 32 + f]);
    }
    return;
  }
  // partA
  int pb = b - (CVTB + 2);
  for (int i = t; i < NBK; i += 256) hist[i] = 0;
  __syncthreads();
  unsigned pk[16]; int bk[16];
  int e0 = pb * 4096 + t;
#pragma unroll
  for (int j = 0; j < 16; ++j) {
    int e = e0 + j * 256;
    if (e < NE) {
      int d = dst[e], s = src[e];
      bk[j] = d >> 9;
      pk[j] = ((unsigned)s << 9) | (unsigned)(d & 511);
      atomicAdd(&hist[bk[j]], 1);
    } else bk[j] = -1;
  }
  __syncthreads();
  for (int i = t; i < NBK; i += 256) {
    base[i] = atomicAdd(&gcur[i], hist[i]);
    lofs[i] = 0;
  }
  __syncthreads();
#pragma unroll
  for (int j = 0; j < 16; ++j) {
    if (bk[j] >= 0) {
      int lp = base[bk[j]] + atomicAdd(&lofs[bk[j]], 1);
      if (lp < CAPB) pairbuf[(size_t)bk[j] * CAPB + lp] = pk[j];
    }
  }
}

// Pass B: one block (512 thr) per bucket. Count -> prefix -> LDS scatter -> writeout.
__global__ void k_partB(const unsigned* __restrict__ pairbuf, const int* __restrict__ gcur,
                        int* __restrict__ esrc, int* __restrict__ rowbeg,
                        int* __restrict__ rowend, float* __restrict__ invd) {
  __shared__ int cnt[512], cur[512], ssum[512];
  __shared__ int ebuf[CAPB];
  int b = blockIdx.x, t = threadIdx.x;
  int cb = gcur[b]; if (cb > CAPB) cb = CAPB;
  cnt[t] = 0;
  __syncthreads();
  const unsigned* pb = pairbuf + (size_t)b * CAPB;
  for (int i = t; i < cb; i += 512) atomicAdd(&cnt[pb[i] & 511], 1);
  __syncthreads();
  int a0 = cnt[t];
  ssum[t] = a0;
  __syncthreads();
  for (int off = 1; off < 512; off <<= 1) {
    int tmp = (t >= off) ? ssum[t - off] : 0;
    __syncthreads();
    ssum[t] += tmp;
    __syncthreads();
  }
  int ex = ssum[t] - a0;
  cur[t] = ex;
  __syncthreads();
  int n = b * 512 + t;
  if (n < NN) {
    rowbeg[n] = b * CAPB + ex;
    rowend[n] = b * CAPB + ex + a0;
    invd[n] = 1.0f / (float)(a0 > 0 ? a0 : 1);
  }
  for (int i = t; i < cb; i += 512) {
    unsigned p = pb[i];
    int pos = atomicAdd(&cur[p & 511], 1);
    ebuf[pos] = (int)(p >> 9);
  }
  __syncthreads();
  for (int i = t; i < cb; i += 512) esrc[(size_t)b * CAPB + i] = ebuf[i];
}

// One wave per node; quarter-wave per edge (dwordx2 rows), 64 edges in flight.
// Indices: one vector load per 64-edge round, broadcast via shfl.
// NOTE: the __shfl MUST be outside the e<rem guard — ds_bpermute only exchanges
// among ACTIVE lanes; a masked-off source lane returns garbage (R5 bug).
__global__ void k_agg(const uint2* __restrict__ fb64, const int* __restrict__ rowbeg,
                      const int* __restrict__ rowend, const int* __restrict__ esrc,
                      const float* __restrict__ invd, uint2* __restrict__ aggb64) {
  int w = (blockIdx.x * blockDim.x + threadIdx.x) >> 6;
  int lane = threadIdx.x & 63;
  int q = lane >> 4, c16 = lane & 15;
  int beg = __builtin_amdgcn_readfirstlane(rowbeg[w]);
  int end = __builtin_amdgcn_readfirstlane(rowend[w]);
  int nume = end - beg;
  float a0 = 0.f, a1 = 0.f, a2 = 0.f, a3 = 0.f;

  for (int r0 = 0; r0 < nume; r0 += 64) {
    int rem = nume - r0; if (rem > 64) rem = 64;
    int idxv = esrc[beg + r0 + (lane < rem ? lane : 0)];
#pragma unroll 4
    for (int j = 0; 4 * j < rem; ++j) {
      int e = 4 * j + q;
      int s = __shfl(idxv, e);   // full-exec shfl: all source lanes active
      if (e < rem) {
        uint2 v = fb64[(size_t)s * 16 + c16];
        a0 += __uint_as_float(v.x << 16);
        a1 += __uint_as_float(v.x & 0xFFFF0000u);
        a2 += __uint_as_float(v.y << 16);
        a3 += __uint_as_float(v.y & 0xFFFF0000u);
      }
    }
  }
  // reduce across quarters
  a0 += __shfl_xor(a0, 16); a1 += __shfl_xor(a1, 16);
  a2 += __shfl_xor(a2, 16); a3 += __shfl_xor(a3, 16);
  a0 += __shfl_xor(a0, 32); a1 += __shfl_xor(a1, 32);
  a2 += __shfl_xor(a2, 32); a3 += __shfl_xor(a3, 32);
  if (lane < 16) {
    float inv = invd[w];
    uint2 o;
    o.x = (unsigned)f2b(a0 * inv) | ((unsigned)f2b(a1 * inv) << 16);
    o.y = (unsigned)f2b(a2 * inv) | ((unsigned)f2b(a3 * inv) << 16);
    aggb64[(size_t)w * 16 + c16] = o;
  }
}

// MFMA GEMM: out[n][f] = sum_k [aggb|featb][n][k] * WT[f][k] + bias[f], K=128 bf16.
template <int NF>
__global__ __launch_bounds__(256) void k_gemm(
    const unsigned short* __restrict__ aggb, const unsigned short* __restrict__ featb,
    const unsigned short* __restrict__ WT, const float* __restrict__ bias,
    float* __restrict__ out, unsigned short* __restrict__ ob, int relu) {
  __shared__ unsigned short As[64 * 128];
  __shared__ unsigned short Ws[NF * 128];
  int tid = threadIdx.x;
  int n0 = blockIdx.x * 64;
  int lane = tid & 63, wr = tid >> 6;

  for (int cch = tid; cch < 64 * 16; cch += 256) {
    int r = cch >> 4, s = cch & 15;
    int n = n0 + r;
    bf16x8 v = {0, 0, 0, 0, 0, 0, 0, 0};
    if (n < NN) {
      const unsigned short* p = (s < 8) ? (aggb + (size_t)n * 64 + s * 8)
                                        : (featb + (size_t)n * 64 + (s - 8) * 8);
      v = *(const bf16x8*)p;
    }
    *(bf16x8*)(&As[r * 128 + ((s ^ (r & 15)) << 3)]) = v;
  }
  for (int cch = tid; cch < NF * 16; cch += 256) {
    int f = cch >> 4, s = cch & 15;
    bf16x8 v = *(const bf16x8*)(WT + f * 128 + s * 8);
    *(bf16x8*)(&Ws[f * 128 + ((s ^ (f & 15)) << 3)]) = v;
  }
  __syncthreads();

  int l15 = lane & 15, lg = lane >> 4;
  int arow = wr * 16 + l15;
  f32x4 acc[NF / 16];
#pragma unroll
  for (int ct = 0; ct < NF / 16; ++ct) acc[ct] = (f32x4){0.f, 0.f, 0.f, 0.f};

#pragma unroll
  for (int k0 = 0; k0 < 4; ++k0) {
    int sa = k0 * 4 + lg;
    bf16x8 a = *(const bf16x8*)(&As[arow * 128 + ((sa ^ (arow & 15)) << 3)]);
#pragma unroll
    for (int ct = 0; ct < NF / 16; ++ct) {
      int bcol = ct * 16 + l15;
      bf16x8 b = *(const bf16x8*)(&Ws[bcol * 128 + ((sa ^ (bcol & 15)) << 3)]);
      acc[ct] = __builtin_amdgcn_mfma_f32_16x16x32_bf16(a, b, acc[ct], 0, 0, 0);
    }
  }

#pragma unroll
  for (int ct = 0; ct < NF / 16; ++ct) {
    int f = ct * 16 + l15;
    float bv = bias[f];
#pragma unroll
    for (int r = 0; r < 4; ++r) {
      int n = n0 + wr * 16 + lg * 4 + r;
      if (n >= NN) continue;
      float v = acc[ct][r] + bv;
      if (relu) v = fmaxf(v, 0.f);
      if (out) out[(size_t)n * NF + f] = v;
      if (ob) ob[(size_t)n * NF + f] = f2b(v);
    }
  }
}

extern "C" void kernel_launch(void* const* d_in, const int* in_sizes, int n_in,
                              void* d_out, int out_size, void* d_ws, size_t ws_size,
                              hipStream_t stream) {
  const float* x   = (const float*)d_in[0];
  const int*   ei  = (const int*)d_in[1];
  const float* W1l = (const float*)d_in[2];
  const float* W1r = (const float*)d_in[3];
  const float* b1  = (const float*)d_in[4];
  const float* W2l = (const float*)d_in[5];
  const float* W2r = (const float*)d_in[6];
  const float* b2  = (const float*)d_in[7];
  const int* src = ei;
  const int* dst = ei + NE;
  float* out = (float*)d_out;

  char* ws = (char*)d_ws;
  size_t off = 0;
  auto take = [&](size_t bytes) -> char* {
    char* p = ws + off;
    off = (off + bytes + 255) & ~(size_t)255;
    return p;
  };
  int*      gcur    = (int*)take((size_t)NBK * 4);
  unsigned* pairbuf = (unsigned*)take((size_t)NBK * CAPB * 4);
  int*      esrc    = (int*)take((size_t)NBK * CAPB * 4);
  int*      rowbeg  = (int*)take((size_t)NN * 4);
  int*      rowend  = (int*)take((size_t)NN * 4);
  float*    invd    = (float*)take((size_t)NN * 4);
  unsigned short* aggb = (unsigned short*)take((size_t)NN * 64 * 2);
  unsigned short* xb   = (unsigned short*)take((size_t)NN * 64 * 2);
  unsigned short* hb   = (unsigned short*)take((size_t)NN * 64 * 2);
  unsigned short* WT1  = (unsigned short*)take((size_t)64 * 128 * 2);
  unsigned short* WT2  = (unsigned short*)take((size_t)32 * 128 * 2);

  hipMemsetAsync(gcur, 0, (size_t)NBK * 4, stream);

  int nbA = (NE + 4095) / 4096;  // 391
  k_pre<<<CVTB + 2 + nbA, 256, 0, stream>>>(x, xb, W1l, W1r, WT1, W2l, W2r, WT2,
                                            src, dst, gcur, pairbuf);
  k_partB<<<NBK, 512, 0, stream>>>(pairbuf, gcur, esrc, rowbeg, rowend, invd);

  int nbG = (NN + 63) / 64;  // 1563
  // layer 1
  k_agg<<<(NN * 64) / 256, 256, 0, stream>>>((const uint2*)xb, rowbeg, rowend, esrc,
                                             invd, (uint2*)aggb);
  k_gemm<64><<<nbG, 256, 0, stream>>>(aggb, xb, WT1, b1, nullptr, hb, 1);
  // layer 2
  k_agg<<<(NN * 64) / 256, 256, 0, stream>>>((const uint2*)hb, rowbeg, rowend, esrc,
                                             invd, (uint2*)aggb);
  k_gemm<32><<<nbG, 256, 0, stream>>>(aggb, hb, WT2, b2, out, nullptr, 0);
}

// Round 7
// 158.155 us; speedup vs baseline: 3.3736x; 1.0919x over previous
//
#include <hip/hip_runtime.h>

#define NN 100000
#define NE 1600000
#define NBK 196        // ceil(100000/512) buckets of 512 nodes
#define CAPB 12288     // per-bucket edge capacity (mean 8192)
#define CVTB 6250      // (NN*64)/1024 blocks for x->bf16

typedef __attribute__((ext_vector_type(8))) short bf16x8;
typedef __attribute__((ext_vector_type(4))) float f32x4;

__device__ __forceinline__ unsigned short f2b(float f) {
  unsigned b = __float_as_uint(f);
  unsigned r = b + 0x7FFF + ((b >> 16) & 1);  // RNE
  return (unsigned short)(r >> 16);
}

// Fused prologue: [0,CVTB) x->bf16 | CVTB: WT1 | CVTB+1: WT2 | rest: partA
__global__ void k_pre(const float* __restrict__ x, unsigned short* __restrict__ xb,
                      const float* __restrict__ W1l, const float* __restrict__ W1r,
                      unsigned short* __restrict__ WT1,
                      const float* __restrict__ W2l, const float* __restrict__ W2r,
                      unsigned short* __restrict__ WT2,
                      const int* __restrict__ src, const int* __restrict__ dst,
                      int* __restrict__ gcur, unsigned* __restrict__ pairbuf) {
  __shared__ int hist[NBK], base[NBK], lofs[NBK];
  int t = threadIdx.x;
  int b = blockIdx.x;
  if (b < CVTB) {
    int i = (b * 256 + t) * 4;
    float4 v = *(const float4*)(x + i);
    ushort4 o;
    o.x = f2b(v.x); o.y = f2b(v.y); o.z = f2b(v.z); o.w = f2b(v.w);
    *(ushort4*)(xb + i) = o;
    return;
  }
  if (b == CVTB) {
    for (int i = t; i < 64 * 128; i += 256) {
      int f = i >> 7, k = i & 127;
      WT1[i] = f2b((k < 64) ? W1l[k * 64 + f] : W1r[(k - 64) * 64 + f]);
    }
    return;
  }
  if (b == CVTB + 1) {
    for (int i = t; i < 32 * 128; i += 256) {
      int f = i >> 7, k = i & 127;
      WT2[i] = f2b((k < 64) ? W2l[k * 32 + f] : W2r[(k - 64) * 32 + f]);
    }
    return;
  }
  // partA
  int pb = b - (CVTB + 2);
  for (int i = t; i < NBK; i += 256) hist[i] = 0;
  __syncthreads();
  unsigned pk[16]; int bk[16];
  int e0 = pb * 4096 + t;
#pragma unroll
  for (int j = 0; j < 16; ++j) {
    int e = e0 + j * 256;
    if (e < NE) {
      int d = dst[e], s = src[e];
      bk[j] = d >> 9;
      pk[j] = ((unsigned)s << 9) | (unsigned)(d & 511);
      atomicAdd(&hist[bk[j]], 1);
    } else bk[j] = -1;
  }
  __syncthreads();
  for (int i = t; i < NBK; i += 256) {
    base[i] = atomicAdd(&gcur[i], hist[i]);
    lofs[i] = 0;
  }
  __syncthreads();
#pragma unroll
  for (int j = 0; j < 16; ++j) {
    if (bk[j] >= 0) {
      int lp = base[bk[j]] + atomicAdd(&lofs[bk[j]], 1);
      if (lp < CAPB) pairbuf[(size_t)bk[j] * CAPB + lp] = pk[j];
    }
  }
}

// Pass B: one block (512 thr) per bucket. Count -> prefix -> LDS scatter -> writeout.
// Emits packed rowp2[n] = (beg, end).
__global__ void k_partB(const unsigned* __restrict__ pairbuf, const int* __restrict__ gcur,
                        int* __restrict__ esrc, uint2* __restrict__ rowp2) {
  __shared__ int cnt[512], cur[512], ssum[512];
  __shared__ int ebuf[CAPB];
  int b = blockIdx.x, t = threadIdx.x;
  int cb = gcur[b]; if (cb > CAPB) cb = CAPB;
  cnt[t] = 0;
  __syncthreads();
  const unsigned* pb = pairbuf + (size_t)b * CAPB;
  for (int i = t; i < cb; i += 512) atomicAdd(&cnt[pb[i] & 511], 1);
  __syncthreads();
  int a0 = cnt[t];
  ssum[t] = a0;
  __syncthreads();
  for (int off = 1; off < 512; off <<= 1) {
    int tmp = (t >= off) ? ssum[t - off] : 0;
    __syncthreads();
    ssum[t] += tmp;
    __syncthreads();
  }
  int ex = ssum[t] - a0;
  cur[t] = ex;
  __syncthreads();
  int n = b * 512 + t;
  if (n < NN) rowp2[n] = make_uint2((unsigned)(b * CAPB + ex),
                                    (unsigned)(b * CAPB + ex + a0));
  for (int i = t; i < cb; i += 512) {
    unsigned p = pb[i];
    int pos = atomicAdd(&cur[p & 511], 1);
    ebuf[pos] = (int)(p >> 9);
  }
  __syncthreads();
  for (int i = t; i < cb; i += 512) esrc[(size_t)b * CAPB + i] = ebuf[i];
}

// One node per QUARTER-wave (16 lanes): 4 independent latency chains per wave.
// Per j-iter the quarter gathers one full 128B row (16 x dwordx2), j uniform
// per quarter -> no masked gathers; shfl sources are whole-quarter-active
// (degree is quarter-uniform), so the R5 exec hazard cannot occur.
__global__ void k_agg(const uint2* __restrict__ fb64, const uint2* __restrict__ rowp2,
                      const int* __restrict__ esrc, uint2* __restrict__ aggb64) {
  int tid = blockIdx.x * 256 + threadIdx.x;
  int node = tid >> 4;
  int c16 = tid & 15;
  int qbase = (threadIdx.x & 63) & 48;  // quarter's base lane in wave
  uint2 rp = rowp2[node];
  int beg = (int)rp.x, deg = (int)(rp.y - rp.x);
  float a0 = 0.f, a1 = 0.f, a2 = 0.f, a3 = 0.f;

  for (int r0 = 0; r0 < deg; r0 += 16) {
    int rem = deg - r0; if (rem > 16) rem = 16;
    int idxv = esrc[beg + r0 + (c16 < rem ? c16 : 0)];
#pragma unroll 8
    for (int j = 0; j < rem; ++j) {
      int s = __shfl(idxv, qbase + j);
      uint2 v = fb64[(size_t)s * 16 + c16];
      a0 += __uint_as_float(v.x << 16);
      a1 += __uint_as_float(v.x & 0xFFFF0000u);
      a2 += __uint_as_float(v.y << 16);
      a3 += __uint_as_float(v.y & 0xFFFF0000u);
    }
  }
  float inv = (deg > 0) ? (1.0f / (float)deg) : 0.f;
  uint2 o;
  o.x = (unsigned)f2b(a0 * inv) | ((unsigned)f2b(a1 * inv) << 16);
  o.y = (unsigned)f2b(a2 * inv) | ((unsigned)f2b(a3 * inv) << 16);
  aggb64[(size_t)node * 16 + c16] = o;
}

// MFMA GEMM: out[n][f] = sum_k [aggb|featb][n][k] * WT[f][k] + bias[f], K=128 bf16.
template <int NF>
__global__ __launch_bounds__(256) void k_gemm(
    const unsigned short* __restrict__ aggb, const unsigned short* __restrict__ featb,
    const unsigned short* __restrict__ WT, const float* __restrict__ bias,
    float* __restrict__ out, unsigned short* __restrict__ ob, int relu) {
  __shared__ unsigned short As[64 * 128];
  __shared__ unsigned short Ws[NF * 128];
  int tid = threadIdx.x;
  int n0 = blockIdx.x * 64;
  int lane = tid & 63, wr = tid >> 6;

  for (int cch = tid; cch < 64 * 16; cch += 256) {
    int r = cch >> 4, s = cch & 15;
    int n = n0 + r;
    bf16x8 v = {0, 0, 0, 0, 0, 0, 0, 0};
    if (n < NN) {
      const unsigned short* p = (s < 8) ? (aggb + (size_t)n * 64 + s * 8)
                                        : (featb + (size_t)n * 64 + (s - 8) * 8);
      v = *(const bf16x8*)p;
    }
    *(bf16x8*)(&As[r * 128 + ((s ^ (r & 15)) << 3)]) = v;
  }
  for (int cch = tid; cch < NF * 16; cch += 256) {
    int f = cch >> 4, s = cch & 15;
    bf16x8 v = *(const bf16x8*)(WT + f * 128 + s * 8);
    *(bf16x8*)(&Ws[f * 128 + ((s ^ (f & 15)) << 3)]) = v;
  }
  __syncthreads();

  int l15 = lane & 15, lg = lane >> 4;
  int arow = wr * 16 + l15;
  f32x4 acc[NF / 16];
#pragma unroll
  for (int ct = 0; ct < NF / 16; ++ct) acc[ct] = (f32x4){0.f, 0.f, 0.f, 0.f};

#pragma unroll
  for (int k0 = 0; k0 < 4; ++k0) {
    int sa = k0 * 4 + lg;
    bf16x8 a = *(const bf16x8*)(&As[arow * 128 + ((sa ^ (arow & 15)) << 3)]);
#pragma unroll
    for (int ct = 0; ct < NF / 16; ++ct) {
      int bcol = ct * 16 + l15;
      bf16x8 b = *(const bf16x8*)(&Ws[bcol * 128 + ((sa ^ (bcol & 15)) << 3)]);
      acc[ct] = __builtin_amdgcn_mfma_f32_16x16x32_bf16(a, b, acc[ct], 0, 0, 0);
    }
  }

#pragma unroll
  for (int ct = 0; ct < NF / 16; ++ct) {
    int f = ct * 16 + l15;
    float bv = bias[f];
#pragma unroll
    for (int r = 0; r < 4; ++r) {
      int n = n0 + wr * 16 + lg * 4 + r;
      if (n >= NN) continue;
      float v = acc[ct][r] + bv;
      if (relu) v = fmaxf(v, 0.f);
      if (out) out[(size_t)n * NF + f] = v;
      if (ob) ob[(size_t)n * NF + f] = f2b(v);
    }
  }
}

extern "C" void kernel_launch(void* const* d_in, const int* in_sizes, int n_in,
                              void* d_out, int out_size, void* d_ws, size_t ws_size,
                              hipStream_t stream) {
  const float* x   = (const float*)d_in[0];
  const int*   ei  = (const int*)d_in[1];
  const float* W1l = (const float*)d_in[2];
  const float* W1r = (const float*)d_in[3];
  const float* b1  = (const float*)d_in[4];
  const float* W2l = (const float*)d_in[5];
  const float* W2r = (const float*)d_in[6];
  const float* b2  = (const float*)d_in[7];
  const int* src = ei;
  const int* dst = ei + NE;
  float* out = (float*)d_out;

  char* ws = (char*)d_ws;
  size_t off = 0;
  auto take = [&](size_t bytes) -> char* {
    char* p = ws + off;
    off = (off + bytes + 255) & ~(size_t)255;
    return p;
  };
  int*      gcur    = (int*)take((size_t)NBK * 4);
  unsigned* pairbuf = (unsigned*)take((size_t)NBK * CAPB * 4);
  int*      esrc    = (int*)take((size_t)NBK * CAPB * 4);
  uint2*    rowp2   = (uint2*)take((size_t)NN * 8);
  unsigned short* aggb = (unsigned short*)take((size_t)NN * 64 * 2);
  unsigned short* xb   = (unsigned short*)take((size_t)NN * 64 * 2);
  unsigned short* hb   = (unsigned short*)take((size_t)NN * 64 * 2);
  unsigned short* WT1  = (unsigned short*)take((size_t)64 * 128 * 2);
  unsigned short* WT2  = (unsigned short*)take((size_t)32 * 128 * 2);

  hipMemsetAsync(gcur, 0, (size_t)NBK * 4, stream);

  int nbA = (NE + 4095) / 4096;  // 391
  k_pre<<<CVTB + 2 + nbA, 256, 0, stream>>>(x, xb, W1l, W1r, WT1, W2l, W2r, WT2,
                                            src, dst, gcur, pairbuf);
  k_partB<<<NBK, 512, 0, stream>>>(pairbuf, gcur, esrc, rowp2);

  int nbG = (NN + 63) / 64;  // 1563
  // layer 1: 16 nodes per 256-thr block
  k_agg<<<NN / 16, 256, 0, stream>>>((const uint2*)xb, rowp2, esrc, (uint2*)aggb);
  k_gemm<64><<<nbG, 256, 0, stream>>>(aggb, xb, WT1, b1, nullptr, hb, 1);
  // layer 2
  k_agg<<<NN / 16, 256, 0, stream>>>((const uint2*)hb, rowp2, esrc, (uint2*)aggb);
  k_gemm<32><<<nbG, 256, 0, stream>>>(aggb, hb, WT2, b2, out, nullptr, 0);
}